// Round 16
// baseline (96.025 us; speedup 1.0000x reference)
//
#include <hip/hip_runtime.h>
#include <stdint.h>

typedef short short8 __attribute__((ext_vector_type(8)));
typedef float f32x4 __attribute__((ext_vector_type(4)));

#define AS1 __attribute__((address_space(1)))
#define AS3 __attribute__((address_space(3)))

__device__ __forceinline__ void gl_lds16(const void* g, void* l) {
  __builtin_amdgcn_global_load_lds((const AS1 unsigned int*)g,
                                   (AS3 unsigned int*)l, 16, 0, 0);
}

__device__ __forceinline__ unsigned short f2bf(float f) {
  union { float f; unsigned int u; } v; v.f = f;
  return (unsigned short)((v.u + (((v.u >> 16) & 1u) + 0x7fffu)) >> 16);
}

// ---------------------------------------------------------------------------
// Pre-pass 1: x [16][256][64][64] fp32 NCHW -> x_t [16][64][64][256] bf16 NHWC
// ---------------------------------------------------------------------------
__global__ __launch_bounds__(256) void xpose_kernel(const float* __restrict__ x,
                                                    unsigned short* __restrict__ xt) {
  __shared__ float tile[64][68];
  const int bid = blockIdx.x;
  const int cchunk = bid & 3;
  const int y = (bid >> 2) & 63;
  const int b = bid >> 8;
  const int t = threadIdx.x;
  const int ci0 = cchunk * 64;

  const int cc = t >> 2;
  const int xo = (t & 3) * 16;
  const float* src = x + (((size_t)(b * 256 + ci0 + cc) * 64 + y) * 64 + xo);
  float4 v0 = ((const float4*)src)[0];
  float4 v1 = ((const float4*)src)[1];
  float4 v2 = ((const float4*)src)[2];
  float4 v3 = ((const float4*)src)[3];
  *(float4*)&tile[cc][xo + 0]  = v0;
  *(float4*)&tile[cc][xo + 4]  = v1;
  *(float4*)&tile[cc][xo + 8]  = v2;
  *(float4*)&tile[cc][xo + 12] = v3;
  __syncthreads();

  const int xpos = t >> 2;
  const int ccg = (t & 3) * 16;
  unsigned int pk[8];
#pragma unroll
  for (int e = 0; e < 8; ++e) {
    unsigned int lo = f2bf(tile[ccg + 2 * e][xpos]);
    unsigned int hi = f2bf(tile[ccg + 2 * e + 1][xpos]);
    pk[e] = lo | (hi << 16);
  }
  unsigned short* dst = xt + ((size_t)(b * 4096 + y * 64 + xpos) * 256 + ci0 + ccg);
  uint4 w0; w0.x = pk[0]; w0.y = pk[1]; w0.z = pk[2]; w0.w = pk[3];
  uint4 w1; w1.x = pk[4]; w1.y = pk[5]; w1.z = pk[6]; w1.w = pk[7];
  ((uint4*)dst)[0] = w0;
  ((uint4*)dst)[1] = w1;
}

// ---------------------------------------------------------------------------
// Pre-pass 2: w [256co][256ci][3][3] fp32 -> w_r [9 tap][256co][256ci] bf16
// ---------------------------------------------------------------------------
__global__ __launch_bounds__(256) void wpack_kernel(const float* __restrict__ w,
                                                    unsigned short* __restrict__ wrp) {
  const int idx = blockIdx.x * 256 + threadIdx.x;
  const int ci = idx & 255;
  const int co = (idx >> 8) & 255;
  const int p = idx >> 16;
  wrp[idx] = f2bf(w[(size_t)(co * 256 + ci) * 9 + p]);
}

// ---------------------------------------------------------------------------
// Main: R13's read-ahead pipeline + T4 counted vmcnt (never 0 mid-loop).
// Tile 256co x 256px, 8 waves (2x4), BK=32, ring-4 x 32KB slots, ahead-3.
// Per K-tile: p0 {read A.m4-7(cur) | stage A(kt+3)} -> 16 MFMA m0-3;
//             p1 {read next tile A.m0-3 + B (slot kt+1, landed 1 tile ago) |
//                 stage B(kt+3)} -> 16 MFMA m4-7;
//             lgkmcnt(8) [read-aheads stay outstanding] + vmcnt(4) [counted:
//             tiles kt+1,kt+2 landed; kt+3's 4 in flight] + barrier.
// Swizzle: R5's slot ^= ((row>>1)&3) — measured 0 bank conflicts.
// WAR: stage at kt writes slot (kt+3)&3 = (kt-1)&3; its readers (p0 of kt-1,
// p1 of kt-2) were consumed by MFMAs before the end-of-(kt-1) barrier.
// ---------------------------------------------------------------------------
__global__ __launch_bounds__(512, 2) void conv_r4p(
    const unsigned short* __restrict__ xt,
    const unsigned short* __restrict__ wrp,
    const float* __restrict__ bias,
    float* __restrict__ out) {
  __shared__ unsigned short lds[4][16384];  // slot: A [0,8192), B [8192,16384)

  const int tid = threadIdx.x;
  const int lane = tid & 63;
  const int wv = tid >> 6;
  const int wm = wv >> 2;     // co half (128)
  const int wn = wv & 3;      // px quarter (64)
  const int bid = blockIdx.x;
  const int tile = (bid & 7) * 32 + (bid >> 3);  // bijective XCD swizzle (256%8==0)
  const int b = tile >> 4;
  const int oh0 = (tile & 15) * 4;

  // ---- staging statics: thread t covers rows {srow, srow+128} ----
  const int srow = tid >> 2;            // 0..127
  const int slin = tid & 3;
  const int sw = slin ^ ((srow >> 1) & 3);   // R5 involution (invariant under +128)
  const unsigned short* gA = wrp + (size_t)srow * 256 + sw * 8;
  const unsigned short* gB[2];
#pragma unroll
  for (int i = 0; i < 2; ++i) {
    const int px = i * 128 + srow;
    const int y = min(oh0 + (px >> 6), 61);
    const int xc = min(px & 63, 61);
    gB[i] = xt + ((size_t)(b * 64 + y) * 64 + xc) * 256 + sw * 8;
  }
  const unsigned dstA = srow * 32 + slin * 8;   // +4096 for +128 rows; B: +8192

  auto stageA = [&](int kt2) {
    const int tap = kt2 >> 3, ci0 = (kt2 & 7) * 32;
    unsigned short* sl = &lds[kt2 & 3][0];
    const unsigned short* g = gA + tap * 65536 + ci0;
    gl_lds16(g, sl + dstA);
    gl_lds16(g + 128 * 256, sl + 4096 + dstA);
  };
  auto stageB = [&](int kt2) {
    const int tap = kt2 >> 3, ci0 = (kt2 & 7) * 32;
    const int kh = (tap * 11) >> 5, kw = tap - kh * 3;
    const int off = (kh * 64 + kw) * 256 + ci0;
    unsigned short* sl = &lds[kt2 & 3][0];
    gl_lds16(gB[0] + off, sl + 8192 + dstA);
    gl_lds16(gB[1] + off, sl + 8192 + 4096 + dstA);
  };

  // ---- fragment statics (R5-verified 0-conflict) ----
  const int l15 = lane & 15;
  const int fsl = ((lane >> 4) ^ ((l15 >> 1) & 3)) * 8;
  int aoff[8], boff[4];
#pragma unroll
  for (int a = 0; a < 8; ++a)
    aoff[a] = (wm * 128 + (a >> 2) * 64 + (a & 3) * 16 + l15) * 32 + fsl;
#pragma unroll
  for (int n = 0; n < 4; ++n)
    boff[n] = 8192 + (wn * 64 + n * 16 + l15) * 32 + fsl;

  f32x4 acc[8][4] = {};

  // prologue: stage tiles 0,1,2 (12/thread); drain tiles 0,1; read tile-0 frags
  stageA(0); stageB(0);
  stageA(1); stageB(1);
  stageA(2); stageB(2);
  asm volatile("s_waitcnt vmcnt(4)" ::: "memory");
  __builtin_amdgcn_s_barrier();

  short8 aC0[4], bC0[4], aC1[4], bC1[4], a2[4];
  {
    const unsigned short* s0 = &lds[0][0];
#pragma unroll
    for (int q = 0; q < 4; ++q) aC0[q] = *(const short8*)(s0 + aoff[q]);
#pragma unroll
    for (int n = 0; n < 4; ++n) bC0[n] = *(const short8*)(s0 + boff[n]);
  }

#define KTILE(KT, AC, BC, ANX, BNX)                                            \
  {                                                                            \
    const int kt_ = (KT);                                                      \
    const unsigned short* s_ = &lds[kt_ & 3][0];                               \
    const unsigned short* sn_ = &lds[(kt_ + 1) & 3][0];                        \
    _Pragma("unroll")                                                          \
    for (int q = 0; q < 4; ++q) a2[q] = *(const short8*)(s_ + aoff[4 + q]);    \
    if (kt_ < 69) stageA(kt_ + 3);                                             \
    __builtin_amdgcn_sched_barrier(0);                                         \
    __builtin_amdgcn_s_setprio(1);                                             \
    _Pragma("unroll")                                                          \
    for (int q = 0; q < 4; ++q)                                                \
      _Pragma("unroll")                                                        \
      for (int n = 0; n < 4; ++n)                                              \
        acc[q][n] = __builtin_amdgcn_mfma_f32_16x16x32_bf16(AC[q], BC[n],      \
                                                            acc[q][n], 0, 0, 0); \
    __builtin_amdgcn_s_setprio(0);                                             \
    if (kt_ < 71) {                                                            \
      _Pragma("unroll")                                                        \
      for (int q = 0; q < 4; ++q) ANX[q] = *(const short8*)(sn_ + aoff[q]);    \
      _Pragma("unroll")                                                        \
      for (int n = 0; n < 4; ++n) BNX[n] = *(const short8*)(sn_ + boff[n]);    \
    }                                                                          \
    if (kt_ < 69) stageB(kt_ + 3);                                             \
    __builtin_amdgcn_sched_barrier(0);                                         \
    __builtin_amdgcn_s_setprio(1);                                             \
    _Pragma("unroll")                                                          \
    for (int q = 0; q < 4; ++q)                                                \
      _Pragma("unroll")                                                        \
      for (int n = 0; n < 4; ++n)                                              \
        acc[4 + q][n] = __builtin_amdgcn_mfma_f32_16x16x32_bf16(a2[q], BC[n],  \
                                                                acc[4 + q][n], 0, 0, 0); \
    __builtin_amdgcn_s_setprio(0);                                             \
    asm volatile("s_waitcnt lgkmcnt(8)" ::: "memory");                         \
    if (kt_ < 69)       asm volatile("s_waitcnt vmcnt(4)" ::: "memory");       \
    else if (kt_ == 69) asm volatile("s_waitcnt vmcnt(0)" ::: "memory");       \
    __builtin_amdgcn_s_barrier();                                              \
  }

  for (int it = 0; it < 36; ++it) {
    KTILE(2 * it,     aC0, bC0, aC1, bC1);   // even tile: consume set0, read set1
    KTILE(2 * it + 1, aC1, bC1, aC0, bC0);   // odd tile: consume set1, read set0
  }
#undef KTILE

  // ---- epilogue: D col=lane&15 -> px, row=(lane>>4)*4+j -> co ----
  const int rb = (lane >> 4) * 4;
  const int colp = lane & 15;
#pragma unroll
  for (int a = 0; a < 8; ++a) {
    const int co = wm * 128 + (a >> 2) * 64 + (a & 3) * 16 + rb;
    float bv[4];
#pragma unroll
    for (int j = 0; j < 4; ++j) bv[j] = bias[co + j];
#pragma unroll
    for (int n = 0; n < 4; ++n) {
      const int px = wn * 64 + n * 16 + colp;
      const int prow = px >> 6, ow = px & 63;
      const int oh = oh0 + prow;
      if (ow < 62 && oh < 62) {
#pragma unroll
        for (int j = 0; j < 4; ++j)
          out[((size_t)(b * 256 + co + j) * 62 + oh) * 62 + ow] = acc[a][n][j] + bv[j];
      }
    }
  }
}

// ---------------------------------------------------------------------------
// Fallback: naive fp32 direct conv (used only if d_ws is too small)
// ---------------------------------------------------------------------------
__global__ __launch_bounds__(256) void conv_naive(const float* __restrict__ x,
                                                  const float* __restrict__ wgt,
                                                  const float* __restrict__ bias,
                                                  float* __restrict__ out) {
  const size_t idx = (size_t)blockIdx.x * 256 + threadIdx.x;
  if (idx >= (size_t)16 * 256 * 62 * 62) return;
  const int ow = (int)(idx % 62);
  size_t r = idx / 62;
  const int oh = (int)(r % 62); r /= 62;
  const int co = (int)(r % 256);
  const int b = (int)(r / 256);
  float s = bias[co];
  for (int ci = 0; ci < 256; ++ci) {
    const float* xp = x + ((size_t)(b * 256 + ci) * 64 + oh) * 64 + ow;
    const float* wp = wgt + (size_t)(co * 256 + ci) * 9;
#pragma unroll
    for (int kh = 0; kh < 3; ++kh)
#pragma unroll
      for (int kw = 0; kw < 3; ++kw)
        s += xp[kh * 64 + kw] * wp[kh * 3 + kw];
  }
  out[idx] = s;
}

extern "C" void kernel_launch(void* const* d_in, const int* in_sizes, int n_in,
                              void* d_out, int out_size, void* d_ws, size_t ws_size,
                              hipStream_t stream) {
  const float* x = (const float*)d_in[0];
  const float* wgt = (const float*)d_in[1];
  const float* bias = (const float*)d_in[2];
  float* out = (float*)d_out;

  const size_t xt_elems = (size_t)16 * 64 * 64 * 256;
  const size_t wr_elems = (size_t)9 * 256 * 256;
  const size_t need = (xt_elems + wr_elems) * sizeof(unsigned short);

  if (ws_size < need) {
    conv_naive<<<61504, 256, 0, stream>>>(x, wgt, bias, out);
    return;
  }

  unsigned short* xt = (unsigned short*)d_ws;
  unsigned short* wrp = xt + xt_elems;

  xpose_kernel<<<4096, 256, 0, stream>>>(x, xt);
  wpack_kernel<<<2304, 256, 0, stream>>>(wgt, wrp);
  conv_r4p<<<256, 512, 0, stream>>>(xt, wrp, bias, out);
}

// Round 20
// 89.556 us; speedup vs baseline: 1.0722x; 1.0722x over previous
//
#include <hip/hip_runtime.h>
#include <stdint.h>

typedef short short8 __attribute__((ext_vector_type(8)));
typedef float f32x4 __attribute__((ext_vector_type(4)));

#define AS1 __attribute__((address_space(1)))
#define AS3 __attribute__((address_space(3)))

__device__ __forceinline__ void gl_lds16(const void* g, void* l) {
  __builtin_amdgcn_global_load_lds((const AS1 unsigned int*)g,
                                   (AS3 unsigned int*)l, 16, 0, 0);
}

__device__ __forceinline__ unsigned short f2bf(float f) {
  union { float f; unsigned int u; } v; v.f = f;
  return (unsigned short)((v.u + (((v.u >> 16) & 1u) + 0x7fffu)) >> 16);
}

// ---------------------------------------------------------------------------
// Pre-pass 1: x [16][256][64][64] fp32 NCHW -> x_t [16][64][64][256] bf16 NHWC
// ---------------------------------------------------------------------------
__global__ __launch_bounds__(256) void xpose_kernel(const float* __restrict__ x,
                                                    unsigned short* __restrict__ xt) {
  __shared__ float tile[64][68];
  const int bid = blockIdx.x;
  const int cchunk = bid & 3;
  const int y = (bid >> 2) & 63;
  const int b = bid >> 8;
  const int t = threadIdx.x;
  const int ci0 = cchunk * 64;

  const int cc = t >> 2;
  const int xo = (t & 3) * 16;
  const float* src = x + (((size_t)(b * 256 + ci0 + cc) * 64 + y) * 64 + xo);
  float4 v0 = ((const float4*)src)[0];
  float4 v1 = ((const float4*)src)[1];
  float4 v2 = ((const float4*)src)[2];
  float4 v3 = ((const float4*)src)[3];
  *(float4*)&tile[cc][xo + 0]  = v0;
  *(float4*)&tile[cc][xo + 4]  = v1;
  *(float4*)&tile[cc][xo + 8]  = v2;
  *(float4*)&tile[cc][xo + 12] = v3;
  __syncthreads();

  const int xpos = t >> 2;
  const int ccg = (t & 3) * 16;
  unsigned int pk[8];
#pragma unroll
  for (int e = 0; e < 8; ++e) {
    unsigned int lo = f2bf(tile[ccg + 2 * e][xpos]);
    unsigned int hi = f2bf(tile[ccg + 2 * e + 1][xpos]);
    pk[e] = lo | (hi << 16);
  }
  unsigned short* dst = xt + ((size_t)(b * 4096 + y * 64 + xpos) * 256 + ci0 + ccg);
  uint4 w0; w0.x = pk[0]; w0.y = pk[1]; w0.z = pk[2]; w0.w = pk[3];
  uint4 w1; w1.x = pk[4]; w1.y = pk[5]; w1.z = pk[6]; w1.w = pk[7];
  ((uint4*)dst)[0] = w0;
  ((uint4*)dst)[1] = w1;
}

// ---------------------------------------------------------------------------
// Pre-pass 2: w [256co][256ci][3][3] fp32 -> w_r [9 tap][256co][256ci] bf16
// ---------------------------------------------------------------------------
__global__ __launch_bounds__(256) void wpack_kernel(const float* __restrict__ w,
                                                    unsigned short* __restrict__ wrp) {
  const int idx = blockIdx.x * 256 + threadIdx.x;
  const int ci = idx & 255;
  const int co = (idx >> 8) & 255;
  const int p = idx >> 16;
  wrp[idx] = f2bf(w[(size_t)(co * 256 + ci) * 9 + p]);
}

// ---------------------------------------------------------------------------
// Main: barrier-light software-pipelined implicit-GEMM conv (R13 schedule,
// RACE-FIXED boundary). R19 diagnosis: raw s_barrier has no IR memory-fence
// semantics -> the post-barrier reload ds_reads could be scheduled BEFORE the
// barrier, reading nbuf regions other waves' gl_lds stages hadn't landed.
// Fix: explicit vmcnt(0) (gl_lds writes are NOT covered by fence lowering)
// then __syncthreads() (true release/acquire fence + barrier) then
// sched_barrier(0) pinning the reloads after it. Emitted waits identical to
// R13's (lgkm0+vmcnt0+barrier) -> same performance, correct ordering.
// ---------------------------------------------------------------------------
__global__ __launch_bounds__(512, 2) void conv_pipe(
    const unsigned short* __restrict__ xt,
    const unsigned short* __restrict__ wrp,
    const float* __restrict__ bias,
    float* __restrict__ out) {
  __shared__ unsigned short lds[2][32768];  // per buf: A [0,16384), B [16384,32768) elems

  const int tid = threadIdx.x;
  const int lane = tid & 63;
  const int wv = tid >> 6;
  const int wm = wv >> 2;     // co half (128)
  const int wn = wv & 3;      // px quarter (64)
  const int bid = blockIdx.x;
  const int tile = (bid & 7) * 32 + (bid >> 3);  // bijective XCD swizzle (256%8==0)
  const int b = tile >> 4;
  const int oh0 = (tile & 15) * 4;

  // ---- staging statics: chunk = 64 rows x k64 = 8KB ----
  const int crow = tid >> 3;            // 0..63
  const int cslot = tid & 7;            // 16B slot
  const int sw = cslot ^ (crow & 7);    // inverse-swizzled source slot
  const unsigned short* gAbase = wrp + (size_t)crow * 256 + sw * 8;
  const unsigned short* gBbase[4];
#pragma unroll
  for (int cb = 0; cb < 4; ++cb) {
    const int y = min(oh0 + cb, 61);
    const int x = min(crow, 61);
    gBbase[cb] = xt + ((size_t)(b * 64 + y) * 64 + x) * 256 + sw * 8;
  }
  const unsigned dst_rc = crow * 64 + cslot * 8;

  // ---- fragment statics (measured 0-conflict) ----
  const int l15 = lane & 15;
  int s8v[2];
  s8v[0] = (((lane >> 4)) ^ (lane & 7)) * 8;
  s8v[1] = (((lane >> 4) + 4) ^ (lane & 7)) * 8;
  int arow[8], brow[4];
#pragma unroll
  for (int a = 0; a < 8; ++a)
    arow[a] = (wm * 128 + (a >> 2) * 64 + (a & 3) * 16 + l15) * 64;
#pragma unroll
  for (int n = 0; n < 4; ++n)
    brow[n] = 16384 + (wn * 64 + n * 16 + l15) * 64;

  auto stageA = [&](int kt2, unsigned short* bufp) {
    const int tap = kt2 >> 2, ci0 = (kt2 & 3) * 64;
    const unsigned short* g = gAbase + tap * 65536 + ci0;
#pragma unroll
    for (int c = 0; c < 4; ++c)
      gl_lds16(g + c * 16384, bufp + c * 4096 + dst_rc);
  };
  auto stageB = [&](int kt2, unsigned short* bufp) {
    const int tap = kt2 >> 2, ci0 = (kt2 & 3) * 64;
    const int kh = (tap * 11) >> 5, kw = tap - kh * 3;
    const int off = (kh * 64 + kw) * 256 + ci0;
#pragma unroll
    for (int cb = 0; cb < 4; ++cb)
      gl_lds16(gBbase[cb] + off, bufp + (4 + cb) * 4096 + dst_rc);
  };

  f32x4 acc[8][4] = {};
  unsigned short* buf0 = &lds[0][0];
  unsigned short* buf1 = &lds[1][0];

  // prologue: stage K-tile 0 fully; drain; fenced barrier; load p0 fragments
  stageA(0, buf0);
  stageB(0, buf0);
  asm volatile("s_waitcnt vmcnt(0)" ::: "memory");  // gl_lds not covered by fence
  __syncthreads();
  __builtin_amdgcn_sched_barrier(0);

  short8 a_cur[4], b_cur[4], a_nxt[4], b_nxt[4];
#pragma unroll
  for (int q = 0; q < 4; ++q) a_cur[q] = *(const short8*)(buf0 + arow[q] + s8v[0]);
#pragma unroll
  for (int n = 0; n < 4; ++n) b_cur[n] = *(const short8*)(buf0 + brow[n] + s8v[0]);

  for (int kt = 0; kt < 36; ++kt) {
    const unsigned short* buf = (kt & 1) ? buf1 : buf0;
    unsigned short* nbuf = (kt & 1) ? buf0 : buf1;

    // ---- p0: issue p1 frags (A m4-7 k0) + stage A(kt+1); MFMA m0-3 k0 ----
#pragma unroll
    for (int q = 0; q < 4; ++q) a_nxt[q] = *(const short8*)(buf + arow[4 + q] + s8v[0]);
    if (kt < 35) stageA(kt + 1, nbuf);
    __builtin_amdgcn_sched_barrier(0);
    __builtin_amdgcn_s_setprio(1);
#pragma unroll
    for (int q = 0; q < 4; ++q)
#pragma unroll
      for (int n = 0; n < 4; ++n)
        acc[q][n] = __builtin_amdgcn_mfma_f32_16x16x32_bf16(a_cur[q], b_cur[n], acc[q][n], 0, 0, 0);
    __builtin_amdgcn_s_setprio(0);

    // ---- p1: issue p2 frags (A m0-3 k1, B k1) + stage B(kt+1); MFMA m4-7 k0 ----
#pragma unroll
    for (int q = 0; q < 4; ++q) a_cur[q] = *(const short8*)(buf + arow[q] + s8v[1]);
#pragma unroll
    for (int n = 0; n < 4; ++n) b_nxt[n] = *(const short8*)(buf + brow[n] + s8v[1]);
    if (kt < 35) stageB(kt + 1, nbuf);
    __builtin_amdgcn_sched_barrier(0);
    __builtin_amdgcn_s_setprio(1);
#pragma unroll
    for (int q = 0; q < 4; ++q)
#pragma unroll
      for (int n = 0; n < 4; ++n)
        acc[4 + q][n] = __builtin_amdgcn_mfma_f32_16x16x32_bf16(a_nxt[q], b_cur[n], acc[4 + q][n], 0, 0, 0);
    __builtin_amdgcn_s_setprio(0);

    // ---- p2: issue p3 frags (A m4-7 k1); MFMA m0-3 k1 ----
#pragma unroll
    for (int q = 0; q < 4; ++q) a_nxt[q] = *(const short8*)(buf + arow[4 + q] + s8v[1]);
    __builtin_amdgcn_sched_barrier(0);
    __builtin_amdgcn_s_setprio(1);
#pragma unroll
    for (int q = 0; q < 4; ++q)
#pragma unroll
      for (int n = 0; n < 4; ++n)
        acc[q][n] = __builtin_amdgcn_mfma_f32_16x16x32_bf16(a_cur[q], b_nxt[n], acc[q][n], 0, 0, 0);
    __builtin_amdgcn_s_setprio(0);

    // ---- p3: fenced K-tile boundary; issue next p0 frags; MFMA m4-7 k1 ----
    if (kt < 35) {
      asm volatile("s_waitcnt vmcnt(0)" ::: "memory");  // my kt+1 stages landed
      __syncthreads();                                  // fence+barrier: all stages
                                                        // visible, all reads drained;
                                                        // reloads CANNOT hoist above
      __builtin_amdgcn_sched_barrier(0);
#pragma unroll
      for (int q = 0; q < 4; ++q) a_cur[q] = *(const short8*)(nbuf + arow[q] + s8v[0]);
#pragma unroll
      for (int n = 0; n < 4; ++n) b_cur[n] = *(const short8*)(nbuf + brow[n] + s8v[0]);
    }
    __builtin_amdgcn_sched_barrier(0);
    __builtin_amdgcn_s_setprio(1);
#pragma unroll
    for (int q = 0; q < 4; ++q)
#pragma unroll
      for (int n = 0; n < 4; ++n)
        acc[4 + q][n] = __builtin_amdgcn_mfma_f32_16x16x32_bf16(a_nxt[q], b_nxt[n], acc[4 + q][n], 0, 0, 0);
    __builtin_amdgcn_s_setprio(0);
  }

  // ---- epilogue: D col=lane&15 -> px, row=(lane>>4)*4+j -> co ----
  const int rb = (lane >> 4) * 4;
  const int colp = lane & 15;
#pragma unroll
  for (int a = 0; a < 8; ++a) {
    const int co = wm * 128 + (a >> 2) * 64 + (a & 3) * 16 + rb;
    float bv[4];
#pragma unroll
    for (int j = 0; j < 4; ++j) bv[j] = bias[co + j];
#pragma unroll
    for (int n = 0; n < 4; ++n) {
      const int px = wn * 64 + n * 16 + colp;
      const int prow = px >> 6, ow = px & 63;
      const int oh = oh0 + prow;
      if (ow < 62 && oh < 62) {
#pragma unroll
        for (int j = 0; j < 4; ++j)
          out[((size_t)(b * 256 + co + j) * 62 + oh) * 62 + ow] = acc[a][n][j] + bv[j];
      }
    }
  }
}

// ---------------------------------------------------------------------------
// Fallback: naive fp32 direct conv (used only if d_ws is too small)
// ---------------------------------------------------------------------------
__global__ __launch_bounds__(256) void conv_naive(const float* __restrict__ x,
                                                  const float* __restrict__ wgt,
                                                  const float* __restrict__ bias,
                                                  float* __restrict__ out) {
  const size_t idx = (size_t)blockIdx.x * 256 + threadIdx.x;
  if (idx >= (size_t)16 * 256 * 62 * 62) return;
  const int ow = (int)(idx % 62);
  size_t r = idx / 62;
  const int oh = (int)(r % 62); r /= 62;
  const int co = (int)(r % 256);
  const int b = (int)(r / 256);
  float s = bias[co];
  for (int ci = 0; ci < 256; ++ci) {
    const float* xp = x + ((size_t)(b * 256 + ci) * 64 + oh) * 64 + ow;
    const float* wp = wgt + (size_t)(co * 256 + ci) * 9;
#pragma unroll
    for (int kh = 0; kh < 3; ++kh)
#pragma unroll
      for (int kw = 0; kw < 3; ++kw)
        s += xp[kh * 64 + kw] * wp[kh * 3 + kw];
  }
  out[idx] = s;
}

extern "C" void kernel_launch(void* const* d_in, const int* in_sizes, int n_in,
                              void* d_out, int out_size, void* d_ws, size_t ws_size,
                              hipStream_t stream) {
  const float* x = (const float*)d_in[0];
  const float* wgt = (const float*)d_in[1];
  const float* bias = (const float*)d_in[2];
  float* out = (float*)d_out;

  const size_t xt_elems = (size_t)16 * 64 * 64 * 256;
  const size_t wr_elems = (size_t)9 * 256 * 256;
  const size_t need = (xt_elems + wr_elems) * sizeof(unsigned short);

  if (ws_size < need) {
    conv_naive<<<61504, 256, 0, stream>>>(x, wgt, bias, out);
    return;
  }

  unsigned short* xt = (unsigned short*)d_ws;
  unsigned short* wrp = xt + xt_elems;

  xpose_kernel<<<4096, 256, 0, stream>>>(x, xt);
  wpack_kernel<<<2304, 256, 0, stream>>>(wgt, wrp);
  conv_pipe<<<256, 512, 0, stream>>>(xt, wrp, bias, out);
}